// Round 2
// baseline (164.325 us; speedup 1.0000x reference)
//
#include <hip/hip_runtime.h>

#define NB 16
#define NA 3
#define NC 80
#define NH 76
#define NW 76
#define MAX_GT 50
#define PLANE (NH * NW)       // 5776
#define CH (5 + NC)           // 85
#define IMG 608.0f
#define SIL 0.6f
#define OBJ_SCALE 5.0f
#define BLOCK 256

__device__ __constant__ float c_aw[3] = {1.5f, 2.375f, 5.0f};
__device__ __constant__ float c_ah[3] = {2.0f, 4.5f, 3.5f};

// ws layout (floats):
//   [0, NB*MAX_GT*4)                      gt boxes (gx,gy,gw,gh)
//   [GT4, GT4+NB)                          n_valid (int)
//   [GT4+NB, GT4+2*NB)                     scatter count (int)
//   [GT4+2*NB, +NB*MAX_GT*8)               scatter entries: {key(i32), tx,ty,tw,th,tconf, tcls(i32), pad}
#define GT4 (NB * MAX_GT * 4)
#define ENT_OFF (GT4 + 2 * NB)

__device__ inline float iou_cwh(float x1, float y1, float w1, float h1,
                                float x2, float y2, float w2, float h2) {
    float mx = fminf(x1 - w1 * 0.5f, x2 - w2 * 0.5f);
    float Mx = fmaxf(x1 + w1 * 0.5f, x2 + w2 * 0.5f);
    float my = fminf(y1 - h1 * 0.5f, y2 - h2 * 0.5f);
    float My = fmaxf(y1 + h1 * 0.5f, y2 + h2 * 0.5f);
    float cw = w1 + w2 - (Mx - mx);
    float ch = h1 + h2 - (My - my);
    float carea = (cw <= 0.f || ch <= 0.f) ? 0.f : cw * ch;
    float uarea = w1 * h1 + w2 * h2 - carea;
    return carea / uarea;
}

__device__ inline float sigmoidf(float v) { return 1.f / (1.f + expf(-v)); }

// Pass A: per-batch GT preprocessing + sequential last-wins scatter dedup.
// grid = NB blocks of 64 threads (thread t handles GT t; thread 0 dedups).
__global__ void yolo_prep(const float* __restrict__ out,
                          const float* __restrict__ target,
                          float* __restrict__ ws,
                          float* __restrict__ d_out) {
    int b = blockIdx.x;
    int t = threadIdx.x;
    __shared__ float cand[MAX_GT][8];
    __shared__ int zflag[MAX_GT];

    if (b == 0 && t == 0) d_out[0] = 0.f;

    if (t < MAX_GT) {
        const float* tg = target + (size_t)b * MAX_GT * 5 + t * 5;
        float gcls = tg[0];
        float pxr = tg[1], pyr = tg[2], pwr = tg[3], phr = tg[4];
        float gx = pxr * (float)NW / IMG;
        float gy = pyr * (float)NH / IMG;
        float gw = pwr * (float)NW / IMG;
        float gh = phr * (float)NH / IMG;
        float* gt = ws + ((size_t)b * MAX_GT + t) * 4;
        gt[0] = gx; gt[1] = gy; gt[2] = gw; gt[3] = gh;
        zflag[t] = (pxr == 0.f) ? 1 : 0;

        // best anchor by (0,0,gw,gh) vs (0,0,aw,ah) IOU, first-max wins
        int bn = 0; float best = -1.f;
        for (int a = 0; a < NA; a++) {
            float v = iou_cwh(0.f, 0.f, gw, gh, 0.f, 0.f, c_aw[a], c_ah[a]);
            if (v > best) { best = v; bn = a; }
        }
        int gi = (int)gx, gj = (int)gy;
        int gic = min(max(gi, 0), NW - 1), gjc = min(max(gj, 0), NH - 1);

        // pred box at gathered (clamped) cell
        const float* base = out + (((size_t)b * NA + bn) * CH) * PLANE + (size_t)gjc * NW + gic;
        float o0 = base[0];
        float o1 = base[PLANE];
        float o2 = base[2 * (size_t)PLANE];
        float o3 = base[3 * (size_t)PLANE];
        float px = sigmoidf(o0) + (float)gic;
        float py = sigmoidf(o1) + (float)gjc;
        float pw = expf(o2) * c_aw[bn];
        float ph = expf(o3) * c_ah[bn];
        float iou = iou_cwh(gx, gy, gw, gh, px, py, pw, ph);

        int key = (gi >= 0 && gi < NW && gj >= 0 && gj < NH) ? ((bn * NH + gj) * NW + gi) : -1;
        ((int*)cand[t])[0] = key;
        cand[t][1] = gx - (float)gi;
        cand[t][2] = gy - (float)gj;
        cand[t][3] = logf(gw / c_aw[bn]);
        cand[t][4] = logf(gh / c_ah[bn]);
        cand[t][5] = iou;
        ((int*)cand[t])[6] = (int)gcls;
        cand[t][7] = 0.f;
    }
    __syncthreads();

    if (t == 0) {
        int nv = 0;
        while (nv < MAX_GT && !zflag[nv]) nv++;  // cumprod validity prefix
        int* nvp = (int*)(ws + GT4);
        int* scp = nvp + NB;
        int* ent = (int*)(ws + ENT_OFF + (size_t)b * MAX_GT * 8);
        int cnt = 0;
        for (int u = 0; u < nv; u++) {
            int key = ((int*)cand[u])[0];
            if (key < 0) continue;
            int slot = -1;
            for (int s = 0; s < cnt; s++)
                if (ent[s * 8 + 0] == key) { slot = s; break; }
            if (slot < 0) slot = cnt++;
            for (int q = 0; q < 8; q++) ent[slot * 8 + q] = ((int*)cand[u])[q];
        }
        nvp[b] = nv;
        scp[b] = cnt;
    }
}

// Pass B: one thread per (b,a,j,i) cell; coalesced channel reads;
// max-IOU vs GT boxes in LDS; scatter-list override; CE only at GT cells.
__global__ __launch_bounds__(BLOCK) void yolo_loss_main(const float* __restrict__ out,
                                                        const float* __restrict__ ws,
                                                        float* __restrict__ d_out) {
    const int bpp = (PLANE + BLOCK - 1) / BLOCK;  // 23
    int plane_id = blockIdx.x / bpp;
    int cb = blockIdx.x % bpp;
    int b = plane_id / NA;
    int a = plane_id % NA;
    int cell = cb * BLOCK + threadIdx.x;

    __shared__ float s_gt[MAX_GT * 4];
    __shared__ float s_ent[MAX_GT * 8];
    __shared__ int s_nv, s_cnt;
    __shared__ float red[BLOCK / 64];

    const float* gt = ws + (size_t)b * MAX_GT * 4;
    for (int i = threadIdx.x; i < MAX_GT * 4; i += BLOCK) s_gt[i] = gt[i];
    const float* ent = ws + ENT_OFF + (size_t)b * MAX_GT * 8;
    for (int i = threadIdx.x; i < MAX_GT * 8; i += BLOCK) s_ent[i] = ent[i];
    if (threadIdx.x == 0) {
        s_nv = ((const int*)(ws + GT4))[b];
        s_cnt = ((const int*)(ws + GT4))[NB + b];
    }
    __syncthreads();

    float loss = 0.f;
    if (cell < PLANE) {
        int j = cell / NW, i = cell % NW;
        const float* base = out + ((size_t)(b * NA + a) * CH) * PLANE + cell;
        float o0 = base[0];
        float o1 = base[PLANE];
        float o2 = base[2 * (size_t)PLANE];
        float o3 = base[3 * (size_t)PLANE];
        float o4 = base[4 * (size_t)PLANE];
        float x = sigmoidf(o0), y = sigmoidf(o1), conf = sigmoidf(o4);
        float px = x + (float)i, py = y + (float)j;
        float pw = expf(o2) * c_aw[a], ph = expf(o3) * c_ah[a];

        // cur_ious = max IOU of this pred box vs all valid GT boxes
        float curmax = 0.f;
        int nv = s_nv;
        for (int tt = 0; tt < nv; tt++) {
            float v = iou_cwh(px, py, pw, ph,
                              s_gt[tt * 4 + 0], s_gt[tt * 4 + 1],
                              s_gt[tt * 4 + 2], s_gt[tt * 4 + 3]);
            curmax = fmaxf(curmax, v);
        }
        float cm2 = (curmax > SIL) ? 0.f : 1.f;  // NOOBJ_SCALE = 1

        float tx = 0.5f, ty = 0.5f, tw = 0.f, th = 0.f, tconf = 0.f;
        int tcls = -1;
        int key = (a * NH + j) * NW + i;
        int cnt = s_cnt;
        for (int s = 0; s < cnt; s++) {
            if (((int*)s_ent)[s * 8 + 0] == key) {
                tx = s_ent[s * 8 + 1];
                ty = s_ent[s * 8 + 2];
                tw = s_ent[s * 8 + 3];
                th = s_ent[s * 8 + 4];
                tconf = s_ent[s * 8 + 5];
                tcls = ((int*)s_ent)[s * 8 + 6];
                cm2 = OBJ_SCALE;
                break;
            }
        }

        float dx = x - tx, dy = y - ty, dw = o2 - tw, dh = o3 - th, dc = conf - tconf;
        loss = 0.5f * (dx * dx + dy * dy + dw * dw + dh * dh + cm2 * dc * dc);

        if (tcls >= 0) {
            // CE = m + log(sum exp(logit - m)) - logit[tcls], channels 5..84
            const float* cb0 = base + 5 * (size_t)PLANE;
            float m = -3.4e38f;
            for (int c = 0; c < NC; c++) m = fmaxf(m, cb0[(size_t)c * PLANE]);
            float ssum = 0.f;
            for (int c = 0; c < NC; c++) ssum += expf(cb0[(size_t)c * PLANE] - m);
            loss += m + logf(ssum) - cb0[(size_t)tcls * PLANE];
        }
    }

    // wave (64-lane) shuffle reduce, then cross-wave LDS reduce, one atomic/block
    for (int off = 32; off > 0; off >>= 1) loss += __shfl_down(loss, off);
    if ((threadIdx.x & 63) == 0) red[threadIdx.x >> 6] = loss;
    __syncthreads();
    if (threadIdx.x == 0) {
        float s = 0.f;
        for (int q = 0; q < BLOCK / 64; q++) s += red[q];
        atomicAdd(d_out, s);
    }
}

extern "C" void kernel_launch(void* const* d_in, const int* in_sizes, int n_in,
                              void* d_out, int out_size, void* d_ws, size_t ws_size,
                              hipStream_t stream) {
    const float* out = (const float*)d_in[0];
    const float* target = (const float*)d_in[1];
    float* ws = (float*)d_ws;
    float* o = (float*)d_out;

    hipLaunchKernelGGL(yolo_prep, dim3(NB), dim3(64), 0, stream, out, target, ws, o);

    const int bpp = (PLANE + BLOCK - 1) / BLOCK;  // 23
    hipLaunchKernelGGL(yolo_loss_main, dim3(NB * NA * bpp), dim3(BLOCK), 0, stream,
                       out, ws, o);
}

// Round 3
// 42.833 us; speedup vs baseline: 3.8364x; 3.8364x over previous
//
#include <hip/hip_runtime.h>

#define NB 16
#define NA 3
#define NC 80
#define NH 76
#define NW 76
#define MAX_GT 50
#define PLANE (NH * NW)       // 5776
#define CH (5 + NC)           // 85
#define IMG 608.0f
#define SIL 0.6f
#define OBJ_SCALE 5.0f
#define BLOCK 256

__device__ __constant__ float c_aw[3] = {1.5f, 2.375f, 5.0f};
__device__ __constant__ float c_ah[3] = {2.0f, 4.5f, 3.5f};

// ws layout (floats):
//   [0, GT8)              per-GT extended boxes: x_lo,x_hi,y_lo,y_hi,gw,gh,area,pad
//   [GT8, GT8+NB)         n_valid (int)
//   [GT8+NB, GT8+2NB)     scatter count (int)
//   [ENT_OFF, +NB*MAX_GT*8) scatter entries: {key(i32), tx,ty,tw,th,tconf, tcls(i32), pad}
#define GT8 (NB * MAX_GT * 8)
#define ENT_OFF (GT8 + 2 * NB)

__device__ inline float iou_cwh(float x1, float y1, float w1, float h1,
                                float x2, float y2, float w2, float h2) {
    float mx = fminf(x1 - w1 * 0.5f, x2 - w2 * 0.5f);
    float Mx = fmaxf(x1 + w1 * 0.5f, x2 + w2 * 0.5f);
    float my = fminf(y1 - h1 * 0.5f, y2 - h2 * 0.5f);
    float My = fmaxf(y1 + h1 * 0.5f, y2 + h2 * 0.5f);
    float cw = w1 + w2 - (Mx - mx);
    float ch = h1 + h2 - (My - my);
    float carea = (cw <= 0.f || ch <= 0.f) ? 0.f : cw * ch;
    float uarea = w1 * h1 + w2 * h2 - carea;
    return carea / uarea;
}

__device__ inline float fast_sigmoid(float v) {
    return __builtin_amdgcn_rcpf(1.f + __expf(-v));
}

// Pass A: per-batch GT preprocessing + PARALLEL last-wins scatter dedup in LDS.
// grid = NB blocks of 64 threads (one wave; thread t handles GT t).
__global__ void yolo_prep(const float* __restrict__ out,
                          const float* __restrict__ target,
                          float* __restrict__ ws,
                          float* __restrict__ d_out) {
    int b = blockIdx.x;
    int t = threadIdx.x;
    __shared__ int s_key[64];
    __shared__ float s_val[MAX_GT][8];
    __shared__ int s_cnt;

    if (t == 0) s_cnt = 0;
    if (b == 0 && t == 0) d_out[0] = 0.f;

    float pxr = 1.f;   // nonzero => "valid" for the ballot below
    int key = -1;

    if (t < MAX_GT) {
        const float* tg = target + (size_t)b * MAX_GT * 5 + t * 5;
        float gcls = tg[0];
        pxr = tg[1];
        float pyr = tg[2], pwr = tg[3], phr = tg[4];
        float gx = pxr * (float)NW / IMG;
        float gy = pyr * (float)NH / IMG;
        float gw = pwr * (float)NW / IMG;
        float gh = phr * (float)NH / IMG;

        // extended GT record for the main kernel's division-free IOU loop
        float* gt = ws + ((size_t)b * MAX_GT + t) * 8;
        gt[0] = gx - gw * 0.5f;
        gt[1] = gx + gw * 0.5f;
        gt[2] = gy - gh * 0.5f;
        gt[3] = gy + gh * 0.5f;
        gt[4] = gw;
        gt[5] = gh;
        gt[6] = gw * gh;
        gt[7] = 0.f;

        // best anchor by (0,0,gw,gh) vs (0,0,aw,ah) IOU, first-max wins
        int bn = 0; float best = -1.f;
        for (int a = 0; a < NA; a++) {
            float v = iou_cwh(0.f, 0.f, gw, gh, 0.f, 0.f, c_aw[a], c_ah[a]);
            if (v > best) { best = v; bn = a; }
        }
        int gi = (int)gx, gj = (int)gy;
        int gic = min(max(gi, 0), NW - 1), gjc = min(max(gj, 0), NH - 1);

        // pred box at gathered (clamped) cell
        const float* base = out + (((size_t)b * NA + bn) * CH) * PLANE + (size_t)gjc * NW + gic;
        float o0 = base[0];
        float o1 = base[PLANE];
        float o2 = base[2 * (size_t)PLANE];
        float o3 = base[3 * (size_t)PLANE];
        float px = fast_sigmoid(o0) + (float)gic;
        float py = fast_sigmoid(o1) + (float)gjc;
        float pw = __expf(o2) * c_aw[bn];
        float ph = __expf(o3) * c_ah[bn];
        float iou = iou_cwh(gx, gy, gw, gh, px, py, pw, ph);

        key = (gi >= 0 && gi < NW && gj >= 0 && gj < NH) ? ((bn * NH + gj) * NW + gi) : -1;
        ((int*)s_val[t])[0] = key;
        s_val[t][1] = gx - (float)gi;
        s_val[t][2] = gy - (float)gj;
        s_val[t][3] = __logf(gw / c_aw[bn]);
        s_val[t][4] = __logf(gh / c_ah[bn]);
        s_val[t][5] = iou;
        ((int*)s_val[t])[6] = (int)gcls;
        s_val[t][7] = 0.f;
    }
    s_key[t] = key;

    // validity prefix (cumprod of target_x != 0): nv = first zero position
    unsigned long long zmask = __ballot((t < MAX_GT) && (pxr == 0.f));
    int nv = zmask ? (int)(__ffsll((long long)zmask) - 1) : MAX_GT;
    if (nv > MAX_GT) nv = MAX_GT;
    __syncthreads();

    // last-write-wins: GT t survives iff no later valid GT shares its key
    bool winner = (t < nv) && (s_key[t] >= 0);
    if (winner) {
        for (int u = t + 1; u < nv; u++)
            if (s_key[u] == s_key[t]) { winner = false; break; }
    }
    if (winner) {
        int slot = atomicAdd(&s_cnt, 1);
        float* ent = ws + ENT_OFF + ((size_t)b * MAX_GT + slot) * 8;
        #pragma unroll
        for (int q = 0; q < 8; q++) ent[q] = s_val[t][q];
    }
    __syncthreads();
    if (t == 0) {
        ((int*)(ws + GT8))[b] = nv;
        ((int*)(ws + GT8))[NB + b] = s_cnt;
    }
}

// Pass B: one thread per (b,a,j,i) cell; coalesced channel reads;
// division-free silence test vs GT boxes in LDS; scatter override; CE at GT cells.
__global__ __launch_bounds__(BLOCK) void yolo_loss_main(const float* __restrict__ out,
                                                        const float* __restrict__ ws,
                                                        float* __restrict__ d_out) {
    const int bpp = (PLANE + BLOCK - 1) / BLOCK;  // 23
    int plane_id = blockIdx.x / bpp;
    int cb = blockIdx.x % bpp;
    int b = plane_id / NA;
    int a = plane_id % NA;
    int cell = cb * BLOCK + threadIdx.x;

    __shared__ float s_gt[MAX_GT * 8];
    __shared__ float s_ent[MAX_GT * 8];
    __shared__ int s_nv, s_cnt;
    __shared__ float red[BLOCK / 64];

    const float* gt = ws + (size_t)b * MAX_GT * 8;
    for (int i = threadIdx.x; i < MAX_GT * 8; i += BLOCK) s_gt[i] = gt[i];
    const float* ent = ws + ENT_OFF + (size_t)b * MAX_GT * 8;
    for (int i = threadIdx.x; i < MAX_GT * 8; i += BLOCK) s_ent[i] = ent[i];
    if (threadIdx.x == 0) {
        s_nv = ((const int*)(ws + GT8))[b];
        s_cnt = ((const int*)(ws + GT8))[NB + b];
    }
    __syncthreads();

    float loss = 0.f;
    if (cell < PLANE) {
        int j = cell / NW, i = cell % NW;
        const float* base = out + ((size_t)(b * NA + a) * CH) * PLANE + cell;
        float o0 = base[0];
        float o1 = base[PLANE];
        float o2 = base[2 * (size_t)PLANE];
        float o3 = base[3 * (size_t)PLANE];
        float o4 = base[4 * (size_t)PLANE];
        float x = fast_sigmoid(o0), y = fast_sigmoid(o1), conf = fast_sigmoid(o4);
        float px = x + (float)i, py = y + (float)j;
        float pw = __expf(o2) * c_aw[a], ph = __expf(o3) * c_ah[a];
        float pxlo = px - pw * 0.5f, pxhi = px + pw * 0.5f;
        float pylo = py - ph * 0.5f, pyhi = py + ph * 0.5f;
        float parea = pw * ph;

        // silent iff exists GT with IOU > SIL  <=>  carea > SIL*uarea (uarea>0)
        bool silent = false;
        int nv = s_nv;
        for (int tt = 0; tt < nv; tt++) {
            const float* g = &s_gt[tt * 8];
            float mx = fminf(pxlo, g[0]);
            float Mx = fmaxf(pxhi, g[1]);
            float my = fminf(pylo, g[2]);
            float My = fmaxf(pyhi, g[3]);
            float cw = pw + g[4] - (Mx - mx);
            float chh = ph + g[5] - (My - my);
            float ca = (cw > 0.f && chh > 0.f) ? cw * chh : 0.f;
            float ua = parea + g[6] - ca;
            silent |= (ca > SIL * ua);
        }
        float cm2 = silent ? 0.f : 1.f;  // NOOBJ_SCALE = 1

        float tx = 0.5f, ty = 0.5f, tw = 0.f, th = 0.f, tconf = 0.f;
        int tcls = -1;
        int key = (a * NH + j) * NW + i;
        int cnt = s_cnt;
        for (int s = 0; s < cnt; s++) {
            if (((int*)s_ent)[s * 8 + 0] == key) {
                tx = s_ent[s * 8 + 1];
                ty = s_ent[s * 8 + 2];
                tw = s_ent[s * 8 + 3];
                th = s_ent[s * 8 + 4];
                tconf = s_ent[s * 8 + 5];
                tcls = ((int*)s_ent)[s * 8 + 6];
                cm2 = OBJ_SCALE;
                break;
            }
        }

        float dx = x - tx, dy = y - ty, dw = o2 - tw, dh = o3 - th, dc = conf - tconf;
        loss = 0.5f * (dx * dx + dy * dy + dw * dw + dh * dh + cm2 * dc * dc);

        if (tcls >= 0) {
            // CE = m + log(sum exp(logit - m)) - logit[tcls], channels 5..84
            const float* cb0 = base + 5 * (size_t)PLANE;
            float m = -3.4e38f;
            for (int c = 0; c < NC; c++) m = fmaxf(m, cb0[(size_t)c * PLANE]);
            float ssum = 0.f;
            for (int c = 0; c < NC; c++) ssum += __expf(cb0[(size_t)c * PLANE] - m);
            loss += m + __logf(ssum) - cb0[(size_t)tcls * PLANE];
        }
    }

    // wave (64-lane) shuffle reduce, then cross-wave LDS reduce, one atomic/block
    for (int off = 32; off > 0; off >>= 1) loss += __shfl_down(loss, off);
    if ((threadIdx.x & 63) == 0) red[threadIdx.x >> 6] = loss;
    __syncthreads();
    if (threadIdx.x == 0) {
        float s = 0.f;
        for (int q = 0; q < BLOCK / 64; q++) s += red[q];
        atomicAdd(d_out, s);
    }
}

extern "C" void kernel_launch(void* const* d_in, const int* in_sizes, int n_in,
                              void* d_out, int out_size, void* d_ws, size_t ws_size,
                              hipStream_t stream) {
    const float* out = (const float*)d_in[0];
    const float* target = (const float*)d_in[1];
    float* ws = (float*)d_ws;
    float* o = (float*)d_out;

    hipLaunchKernelGGL(yolo_prep, dim3(NB), dim3(64), 0, stream, out, target, ws, o);

    const int bpp = (PLANE + BLOCK - 1) / BLOCK;  // 23
    hipLaunchKernelGGL(yolo_loss_main, dim3(NB * NA * bpp), dim3(BLOCK), 0, stream,
                       out, ws, o);
}

// Round 4
// 34.390 us; speedup vs baseline: 4.7782x; 1.2455x over previous
//
#include <hip/hip_runtime.h>

#define NB 16
#define NA 3
#define NC 80
#define NH 76
#define NW 76
#define MAX_GT 50
#define PLANE (NH * NW)       // 5776
#define CH (5 + NC)           // 85
#define IMG 608.0f
#define SIL 0.6f
#define OBJSC 5.0f
#define BLOCK 256
#define BPP ((PLANE + BLOCK - 1) / BLOCK)   // 23
#define GRID (NB * NA * BPP)                // 1104

__device__ __constant__ float c_aw[3] = {1.5f, 2.375f, 5.0f};
__device__ __constant__ float c_ah[3] = {2.0f, 4.5f, 3.5f};

__device__ inline float fast_sigmoid(float v) {
    return __builtin_amdgcn_rcpf(1.f + __expf(-v));
}

__device__ inline float iou_full(float x1, float y1, float w1, float h1,
                                 float x2, float y2, float w2, float h2) {
    float mx = fminf(x1 - w1 * 0.5f, x2 - w2 * 0.5f);
    float Mx = fmaxf(x1 + w1 * 0.5f, x2 + w2 * 0.5f);
    float my = fminf(y1 - h1 * 0.5f, y2 - h2 * 0.5f);
    float My = fmaxf(y1 + h1 * 0.5f, y2 + h2 * 0.5f);
    float cw = w1 + w2 - (Mx - mx);
    float ch = h1 + h2 - (My - my);
    float carea = (cw <= 0.f || ch <= 0.f) ? 0.f : cw * ch;
    float uarea = w1 * h1 + w2 * h2 - carea;
    return carea / uarea;
}

// One fused kernel. Each block: (b, a, cell-chunk). Wave 0 redoes the per-batch
// GT prep in LDS (cheap: 50 lanes, gathered loads L2-hit after first block of
// the batch), then all 256 threads do the dense per-cell loss. CE at GT cells
// is wave-cooperative. One atomicAdd per block into d_out (pre-zeroed by a
// memset node).
__global__ __launch_bounds__(BLOCK) void yolo_fused(const float* __restrict__ out,
                                                    const float* __restrict__ target,
                                                    float* __restrict__ d_out) {
    const int bid = blockIdx.x;
    const int plane_id = bid / BPP;
    const int cb = bid % BPP;
    const int b = plane_id / NA;
    const int a = plane_id % NA;
    const int t = threadIdx.x;
    const int cell = cb * BLOCK + t;
    const bool incell = (cell < PLANE);

    __shared__ float4 s_gtA[MAX_GT];          // xlo, xhi, ylo, yhi
    __shared__ float4 s_gtB[MAX_GT];          // gw, gh, area, 0
    __shared__ float s_ent[MAX_GT][8];        // key_f, tx, ty, tw, th, tconf, cls_f, pad
    __shared__ int s_key[64];
    __shared__ int s_ovr[BLOCK];              // cell-local -> entry idx or -1
    __shared__ int s_ce_cell[MAX_GT];
    __shared__ int s_ce_cls[MAX_GT];
    __shared__ int s_nv, s_cnt, s_nce;
    __shared__ float s_red[BLOCK / 64];

    // ---- issue this thread's dense channel loads early (hide under prep) ----
    const float* base = out + ((size_t)(b * NA + a) * CH) * PLANE + cell;
    float o0 = 0.f, o1 = 0.f, o2 = 0.f, o3 = 0.f, o4 = 0.f;
    if (incell) {
        o0 = base[0];
        o1 = base[PLANE];
        o2 = base[2 * (size_t)PLANE];
        o3 = base[3 * (size_t)PLANE];
        o4 = base[4 * (size_t)PLANE];
    }

    s_ovr[t] = -1;
    if (t == 0) { s_cnt = 0; s_nce = 0; }

    // ---- prep: wave 0 only ----
    float e_tx = 0.f, e_ty = 0.f, e_tw = 0.f, e_th = 0.f, e_tc = 0.f, e_cls = 0.f;
    int key = -1;
    if (t < 64) {
        float pxr = 1.f;
        if (t < MAX_GT) {
            const float* tg = target + (size_t)b * MAX_GT * 5 + t * 5;
            float gcls = tg[0];
            pxr = tg[1];
            float gx = tg[1] * (float)NW / IMG;
            float gy = tg[2] * (float)NH / IMG;
            float gw = tg[3] * (float)NW / IMG;
            float gh = tg[4] * (float)NH / IMG;
            s_gtA[t] = make_float4(gx - 0.5f * gw, gx + 0.5f * gw,
                                   gy - 0.5f * gh, gy + 0.5f * gh);
            s_gtB[t] = make_float4(gw, gh, gw * gh, 0.f);

            // best anchor (first-max wins); boxes co-centered at 0
            int bn = 0; float best = -1.f;
            #pragma unroll
            for (int aa = 0; aa < NA; aa++) {
                float ca = fminf(gw, c_aw[aa]) * fminf(gh, c_ah[aa]);
                float ua = gw * gh + c_aw[aa] * c_ah[aa] - ca;
                float v = ca / ua;
                if (v > best) { best = v; bn = aa; }
            }
            int gi = (int)gx, gj = (int)gy;
            int gic = min(max(gi, 0), NW - 1), gjc = min(max(gj, 0), NH - 1);

            const float* pb = out + (((size_t)b * NA + bn) * CH) * PLANE
                              + (size_t)gjc * NW + gic;
            float q0 = pb[0];
            float q1 = pb[PLANE];
            float q2 = pb[2 * (size_t)PLANE];
            float q3 = pb[3 * (size_t)PLANE];
            float ppx = fast_sigmoid(q0) + (float)gic;
            float ppy = fast_sigmoid(q1) + (float)gjc;
            float ppw = __expf(q2) * c_aw[bn];
            float pph = __expf(q3) * c_ah[bn];
            float iou = iou_full(gx, gy, gw, gh, ppx, ppy, ppw, pph);

            key = (gi >= 0 && gi < NW && gj >= 0 && gj < NH)
                      ? ((bn * NH + gj) * NW + gi) : -1;
            e_tx = gx - (float)gi;
            e_ty = gy - (float)gj;
            e_tw = __logf(gw / c_aw[bn]);
            e_th = __logf(gh / c_ah[bn]);
            e_tc = iou;
            e_cls = gcls;
        }
        s_key[t] = key;
        // validity prefix: nv = index of first GT with x == 0
        unsigned long long zm = __ballot((t < MAX_GT) && (pxr == 0.f));
        int nv = zm ? (int)(__ffsll((long long)zm) - 1) : MAX_GT;
        if (t == 0) s_nv = nv;
    }
    __syncthreads();

    // ---- dedup (last-write-wins) + compaction: wave 0 ----
    if (t < 64) {
        int nv = s_nv;
        bool winner = (t < nv) && (key >= 0);
        if (winner) {
            for (int u = t + 1; u < nv; u++)
                if (s_key[u] == key) { winner = false; break; }
        }
        if (winner) {
            int slot = atomicAdd(&s_cnt, 1);
            s_ent[slot][0] = (float)key;   // < 2^24, exact
            s_ent[slot][1] = e_tx;
            s_ent[slot][2] = e_ty;
            s_ent[slot][3] = e_tw;
            s_ent[slot][4] = e_th;
            s_ent[slot][5] = e_tc;
            s_ent[slot][6] = e_cls;
            s_ent[slot][7] = 0.f;
        }
    }
    __syncthreads();

    // ---- scatter entries into this block's per-cell override map ----
    if (t < s_cnt) {
        int k = (int)s_ent[t][0];
        int ae = k / PLANE;
        int rem = k - ae * PLANE;
        int local = rem - cb * BLOCK;
        if (ae == a && local >= 0 && local < BLOCK) s_ovr[local] = t;
    }
    __syncthreads();

    // ---- dense per-cell loss ----
    float loss = 0.f;
    if (incell) {
        int j = cell / NW, i = cell - (cell / NW) * NW;
        float x = fast_sigmoid(o0), y = fast_sigmoid(o1), conf = fast_sigmoid(o4);
        float pw = __expf(o2) * c_aw[a], ph = __expf(o3) * c_ah[a];
        float px = x + (float)i, py = y + (float)j;
        float pxlo = px - 0.5f * pw, pxhi = px + 0.5f * pw;
        float pylo = py - 0.5f * ph, pyhi = py + 0.5f * ph;
        float pa = pw * ph;

        bool silent = false;
        int nv = s_nv;
        #pragma unroll 2
        for (int tt = 0; tt < nv; tt++) {
            float4 gA = s_gtA[tt];
            float4 gB = s_gtB[tt];
            float mx = fminf(pxlo, gA.x), Mx = fmaxf(pxhi, gA.y);
            float my = fminf(pylo, gA.z), My = fmaxf(pyhi, gA.w);
            float cw = pw + gB.x - (Mx - mx);
            float chh = ph + gB.y - (My - my);
            float ca = cw * chh;
            float ua = pa + gB.z - ca;
            silent |= ((cw > 0.f) & (chh > 0.f) & (ca > SIL * ua));
        }
        float cm2 = silent ? 0.f : 1.f;   // NOOBJ_SCALE = 1

        float tx = 0.5f, ty = 0.5f, tw = 0.f, th = 0.f, tconf = 0.f;
        int ov = s_ovr[t];
        if (ov >= 0) {
            tx = s_ent[ov][1];
            ty = s_ent[ov][2];
            tw = s_ent[ov][3];
            th = s_ent[ov][4];
            tconf = s_ent[ov][5];
            cm2 = OBJSC;
            int idx = atomicAdd(&s_nce, 1);
            s_ce_cell[idx] = cell;
            s_ce_cls[idx] = (int)s_ent[ov][6];
        }

        float dx = x - tx, dy = y - ty, dw = o2 - tw, dh = o3 - th, dc = conf - tconf;
        loss = 0.5f * (dx * dx + dy * dy + dw * dw + dh * dh + cm2 * dc * dc);
    }
    __syncthreads();

    // ---- wave-cooperative CE for this block's GT cells ----
    int nce = s_nce;
    int wid = t >> 6, lane = t & 63;
    for (int k = wid; k < nce; k += BLOCK / 64) {
        int ccell = s_ce_cell[k];
        int ccls = s_ce_cls[k];
        const float* cb0 = out + ((size_t)(b * NA + a) * CH + 5) * PLANE + ccell;
        float v1 = cb0[(size_t)lane * PLANE];                       // lanes 0..63
        float v2 = (lane < NC - 64) ? cb0[(size_t)(lane + 64) * PLANE] : -3.4e38f;
        float m = fmaxf(v1, v2);
        #pragma unroll
        for (int off = 32; off; off >>= 1) m = fmaxf(m, __shfl_xor(m, off));
        float e = __expf(v1 - m) + ((lane < NC - 64) ? __expf(v2 - m) : 0.f);
        #pragma unroll
        for (int off = 32; off; off >>= 1) e += __shfl_xor(e, off);
        if (lane == 0) {
            float lt = cb0[(size_t)ccls * PLANE];
            loss += m + __logf(e) - lt;
        }
    }

    // ---- block reduction: wave shuffle -> LDS -> one atomic ----
    #pragma unroll
    for (int off = 32; off; off >>= 1) loss += __shfl_down(loss, off);
    if (lane == 0) s_red[wid] = loss;
    __syncthreads();
    if (t == 0) {
        float s = 0.f;
        #pragma unroll
        for (int q = 0; q < BLOCK / 64; q++) s += s_red[q];
        atomicAdd(d_out, s);
    }
}

extern "C" void kernel_launch(void* const* d_in, const int* in_sizes, int n_in,
                              void* d_out, int out_size, void* d_ws, size_t ws_size,
                              hipStream_t stream) {
    const float* out = (const float*)d_in[0];
    const float* target = (const float*)d_in[1];
    float* o = (float*)d_out;

    hipMemsetAsync(o, 0, sizeof(float), stream);
    hipLaunchKernelGGL(yolo_fused, dim3(GRID), dim3(BLOCK), 0, stream,
                       out, target, o);
}

// Round 5
// 25.231 us; speedup vs baseline: 6.5129x; 1.3630x over previous
//
#include <hip/hip_runtime.h>

#define NB 16
#define NA 3
#define NC 80
#define NH 76
#define NW 76
#define MAX_GT 50
#define PLANE (NH * NW)       // 5776
#define CH (5 + NC)           // 85
#define IMG 608.0f
#define SIL 0.6f
#define OBJSC 5.0f
#define BLOCK 256
#define BPP ((PLANE + BLOCK - 1) / BLOCK)   // 23
#define GRID (NB * NA * BPP)                // 1104

__device__ __constant__ float c_aw[3] = {1.5f, 2.375f, 5.0f};
__device__ __constant__ float c_ah[3] = {2.0f, 4.5f, 3.5f};

__device__ inline float fast_sigmoid(float v) {
    return __builtin_amdgcn_rcpf(1.f + __expf(-v));
}

__device__ inline float iou_full(float x1, float y1, float w1, float h1,
                                 float x2, float y2, float w2, float h2) {
    float mx = fminf(x1 - w1 * 0.5f, x2 - w2 * 0.5f);
    float Mx = fmaxf(x1 + w1 * 0.5f, x2 + w2 * 0.5f);
    float my = fminf(y1 - h1 * 0.5f, y2 - h2 * 0.5f);
    float My = fmaxf(y1 + h1 * 0.5f, y2 + h2 * 0.5f);
    float cw = w1 + w2 - (Mx - mx);
    float ch = h1 + h2 - (My - my);
    float carea = (cw <= 0.f || ch <= 0.f) ? 0.f : cw * ch;
    float uarea = w1 * h1 + w2 * h2 - carea;
    return carea / uarea;
}

// Fused main kernel: block = (b, a, cell-chunk). Wave 0 redoes per-batch GT
// prep in LDS; all 256 threads do the dense per-cell loss; CE at GT cells is
// wave-cooperative. Per-block partial -> d_ws[bid] (NO contended atomic).
__global__ __launch_bounds__(BLOCK) void yolo_fused(const float* __restrict__ out,
                                                    const float* __restrict__ target,
                                                    float* __restrict__ partial) {
    const int bid = blockIdx.x;
    const int plane_id = bid / BPP;
    const int cb = bid % BPP;
    const int b = plane_id / NA;
    const int a = plane_id % NA;
    const int t = threadIdx.x;
    const int cell = cb * BLOCK + t;
    const bool incell = (cell < PLANE);

    __shared__ float4 s_gtA[MAX_GT];          // xlo, xhi, ylo, yhi
    __shared__ float4 s_gtB[MAX_GT];          // gw, gh, area, 0
    __shared__ float s_ent[MAX_GT][8];        // key_f, tx, ty, tw, th, tconf, cls_f, pad
    __shared__ int s_key[64];
    __shared__ int s_ovr[BLOCK];              // cell-local -> entry idx or -1
    __shared__ int s_ce_cell[MAX_GT];
    __shared__ int s_ce_cls[MAX_GT];
    __shared__ int s_nv, s_cnt, s_nce;
    __shared__ float s_red[BLOCK / 64];

    // ---- issue this thread's dense channel loads early (hide under prep) ----
    const float* base = out + ((size_t)(b * NA + a) * CH) * PLANE + cell;
    float o0 = 0.f, o1 = 0.f, o2 = 0.f, o3 = 0.f, o4 = 0.f;
    if (incell) {
        o0 = base[0];
        o1 = base[PLANE];
        o2 = base[2 * (size_t)PLANE];
        o3 = base[3 * (size_t)PLANE];
        o4 = base[4 * (size_t)PLANE];
    }

    s_ovr[t] = -1;
    if (t == 0) { s_cnt = 0; s_nce = 0; }

    // ---- prep: wave 0 only ----
    float e_tx = 0.f, e_ty = 0.f, e_tw = 0.f, e_th = 0.f, e_tc = 0.f, e_cls = 0.f;
    int key = -1;
    if (t < 64) {
        float pxr = 1.f;
        if (t < MAX_GT) {
            const float* tg = target + (size_t)b * MAX_GT * 5 + t * 5;
            float gcls = tg[0];
            pxr = tg[1];
            float gx = tg[1] * (float)NW / IMG;
            float gy = tg[2] * (float)NH / IMG;
            float gw = tg[3] * (float)NW / IMG;
            float gh = tg[4] * (float)NH / IMG;
            s_gtA[t] = make_float4(gx - 0.5f * gw, gx + 0.5f * gw,
                                   gy - 0.5f * gh, gy + 0.5f * gh);
            s_gtB[t] = make_float4(gw, gh, gw * gh, 0.f);

            // best anchor (first-max wins); boxes co-centered at 0
            int bn = 0; float best = -1.f;
            #pragma unroll
            for (int aa = 0; aa < NA; aa++) {
                float ca = fminf(gw, c_aw[aa]) * fminf(gh, c_ah[aa]);
                float ua = gw * gh + c_aw[aa] * c_ah[aa] - ca;
                float v = ca / ua;
                if (v > best) { best = v; bn = aa; }
            }
            int gi = (int)gx, gj = (int)gy;
            int gic = min(max(gi, 0), NW - 1), gjc = min(max(gj, 0), NH - 1);

            const float* pb = out + (((size_t)b * NA + bn) * CH) * PLANE
                              + (size_t)gjc * NW + gic;
            float q0 = pb[0];
            float q1 = pb[PLANE];
            float q2 = pb[2 * (size_t)PLANE];
            float q3 = pb[3 * (size_t)PLANE];
            float ppx = fast_sigmoid(q0) + (float)gic;
            float ppy = fast_sigmoid(q1) + (float)gjc;
            float ppw = __expf(q2) * c_aw[bn];
            float pph = __expf(q3) * c_ah[bn];
            float iou = iou_full(gx, gy, gw, gh, ppx, ppy, ppw, pph);

            key = (gi >= 0 && gi < NW && gj >= 0 && gj < NH)
                      ? ((bn * NH + gj) * NW + gi) : -1;
            e_tx = gx - (float)gi;
            e_ty = gy - (float)gj;
            e_tw = __logf(gw / c_aw[bn]);
            e_th = __logf(gh / c_ah[bn]);
            e_tc = iou;
            e_cls = gcls;
        }
        s_key[t] = key;
        // validity prefix: nv = index of first GT with x == 0
        unsigned long long zm = __ballot((t < MAX_GT) && (pxr == 0.f));
        int nv = zm ? (int)(__ffsll((long long)zm) - 1) : MAX_GT;
        if (t == 0) s_nv = nv;
    }
    __syncthreads();

    // ---- dedup (last-write-wins) + compaction: wave 0 ----
    if (t < 64) {
        int nv = s_nv;
        bool winner = (t < nv) && (key >= 0);
        if (winner) {
            for (int u = t + 1; u < nv; u++)
                if (s_key[u] == key) { winner = false; break; }
        }
        if (winner) {
            int slot = atomicAdd(&s_cnt, 1);
            s_ent[slot][0] = (float)key;   // < 2^24, exact
            s_ent[slot][1] = e_tx;
            s_ent[slot][2] = e_ty;
            s_ent[slot][3] = e_tw;
            s_ent[slot][4] = e_th;
            s_ent[slot][5] = e_tc;
            s_ent[slot][6] = e_cls;
            s_ent[slot][7] = 0.f;
        }
    }
    __syncthreads();

    // ---- scatter entries into this block's per-cell override map ----
    if (t < s_cnt) {
        int k = (int)s_ent[t][0];
        int ae = k / PLANE;
        int rem = k - ae * PLANE;
        int local = rem - cb * BLOCK;
        if (ae == a && local >= 0 && local < BLOCK) s_ovr[local] = t;
    }
    __syncthreads();

    // ---- dense per-cell loss ----
    float loss = 0.f;
    if (incell) {
        int j = cell / NW, i = cell - (cell / NW) * NW;
        float x = fast_sigmoid(o0), y = fast_sigmoid(o1), conf = fast_sigmoid(o4);
        float pw = __expf(o2) * c_aw[a], ph = __expf(o3) * c_ah[a];
        float px = x + (float)i, py = y + (float)j;
        float pxlo = px - 0.5f * pw, pxhi = px + 0.5f * pw;
        float pylo = py - 0.5f * ph, pyhi = py + 0.5f * ph;
        float pa = pw * ph;

        bool silent = false;
        int nv = s_nv;
        #pragma unroll 2
        for (int tt = 0; tt < nv; tt++) {
            float4 gA = s_gtA[tt];
            float4 gB = s_gtB[tt];
            float mx = fminf(pxlo, gA.x), Mx = fmaxf(pxhi, gA.y);
            float my = fminf(pylo, gA.z), My = fmaxf(pyhi, gA.w);
            float cw = pw + gB.x - (Mx - mx);
            float chh = ph + gB.y - (My - my);
            float ca = cw * chh;
            float ua = pa + gB.z - ca;
            silent |= ((cw > 0.f) & (chh > 0.f) & (ca > SIL * ua));
        }
        float cm2 = silent ? 0.f : 1.f;   // NOOBJ_SCALE = 1

        float tx = 0.5f, ty = 0.5f, tw = 0.f, th = 0.f, tconf = 0.f;
        int ov = s_ovr[t];
        if (ov >= 0) {
            tx = s_ent[ov][1];
            ty = s_ent[ov][2];
            tw = s_ent[ov][3];
            th = s_ent[ov][4];
            tconf = s_ent[ov][5];
            cm2 = OBJSC;
            int idx = atomicAdd(&s_nce, 1);
            s_ce_cell[idx] = cell;
            s_ce_cls[idx] = (int)s_ent[ov][6];
        }

        float dx = x - tx, dy = y - ty, dw = o2 - tw, dh = o3 - th, dc = conf - tconf;
        loss = 0.5f * (dx * dx + dy * dy + dw * dw + dh * dh + cm2 * dc * dc);
    }
    __syncthreads();

    // ---- wave-cooperative CE for this block's GT cells ----
    int nce = s_nce;
    int wid = t >> 6, lane = t & 63;
    for (int k = wid; k < nce; k += BLOCK / 64) {
        int ccell = s_ce_cell[k];
        int ccls = s_ce_cls[k];
        const float* cb0 = out + ((size_t)(b * NA + a) * CH + 5) * PLANE + ccell;
        float v1 = cb0[(size_t)lane * PLANE];                       // lanes 0..63
        float v2 = (lane < NC - 64) ? cb0[(size_t)(lane + 64) * PLANE] : -3.4e38f;
        float m = fmaxf(v1, v2);
        #pragma unroll
        for (int off = 32; off; off >>= 1) m = fmaxf(m, __shfl_xor(m, off));
        float e = __expf(v1 - m) + ((lane < NC - 64) ? __expf(v2 - m) : 0.f);
        #pragma unroll
        for (int off = 32; off; off >>= 1) e += __shfl_xor(e, off);
        if (lane == 0) {
            float lt = cb0[(size_t)ccls * PLANE];
            loss += m + __logf(e) - lt;
        }
    }

    // ---- block reduction: wave shuffle -> LDS -> ONE STORE (no atomic) ----
    #pragma unroll
    for (int off = 32; off; off >>= 1) loss += __shfl_down(loss, off);
    if (lane == 0) s_red[wid] = loss;
    __syncthreads();
    if (t == 0) {
        float s = 0.f;
        #pragma unroll
        for (int q = 0; q < BLOCK / 64; q++) s += s_red[q];
        partial[bid] = s;
    }
}

// Final reduction: one block sums the 1104 per-block partials.
__global__ __launch_bounds__(BLOCK) void yolo_reduce(const float* __restrict__ partial,
                                                     float* __restrict__ d_out) {
    int t = threadIdx.x;
    __shared__ float s_red[BLOCK / 64];
    float s = 0.f;
    for (int i = t; i < GRID; i += BLOCK) s += partial[i];
    #pragma unroll
    for (int off = 32; off; off >>= 1) s += __shfl_down(s, off);
    if ((t & 63) == 0) s_red[t >> 6] = s;
    __syncthreads();
    if (t == 0) {
        float tot = 0.f;
        #pragma unroll
        for (int q = 0; q < BLOCK / 64; q++) tot += s_red[q];
        d_out[0] = tot;
    }
}

extern "C" void kernel_launch(void* const* d_in, const int* in_sizes, int n_in,
                              void* d_out, int out_size, void* d_ws, size_t ws_size,
                              hipStream_t stream) {
    const float* out = (const float*)d_in[0];
    const float* target = (const float*)d_in[1];
    float* partial = (float*)d_ws;
    float* o = (float*)d_out;

    hipLaunchKernelGGL(yolo_fused, dim3(GRID), dim3(BLOCK), 0, stream,
                       out, target, partial);
    hipLaunchKernelGGL(yolo_reduce, dim3(1), dim3(BLOCK), 0, stream,
                       partial, o);
}